// Round 8
// baseline (375.540 us; speedup 1.0000x reference)
//
#include <hip/hip_runtime.h>

#define B_  8
#define C_  64
#define OC_ 64
#define H_  256
#define W_  256
#define HW_ (H_ * W_)
#define RPB 8            // rows per block (strip height)

typedef __attribute__((ext_vector_type(4))) float f32x4;
typedef _Float16 h2v __attribute__((ext_vector_type(2)));  // packed fp16 pair
typedef _Float16 h8v __attribute__((ext_vector_type(8)));  // MFMA f16 A/B frag

// chunk-slot swizzle: spreads the 8 16B channel-chunks of a pixel across
// banks keyed by pixel, bijective per px (XOR involution).
__device__ __forceinline__ int swz(int p) { return (p ^ (p >> 3)) & 7; }

// ============================================================================
// Round-10: ring design (round-6/7) pulled back into the PROVEN 128 KB LDS
// envelope. Rounds 6/7 died with errorless container failures; the only
// untested envelope variable vs the passing round-5 kernel was 152 KB static
// LDS. Fix: part/pw/pi time-share the 32 KB stt buffer (as round 5 proved),
// +1 barrier per row. Design unchanged otherwise:
//   - 256 blocks (1/CU), each owns an 8-row strip of one image
//   - 96 KB LDS = 3-slot row ring keyed by y%3; steady state stages ONE new
//     row per output row (vs 3x restage in round-5 = the dominant phase)
//   - stage loads issued at loop top (hide under B+C), written after bar3
//   - w_conv A-fragments hoisted out of the row loop (row-invariant)
// LDS total: 96 (ring) + 32 (stt: part/pw/pi early, S^T late) = 128 KB.
// ============================================================================
__global__ __launch_bounds__(1024, 4) void dcn_fused(
    const float* __restrict__ x,
    const float* __restrict__ w_conv,
    const float* __restrict__ w_off,
    const float* __restrict__ b_off,
    const float* __restrict__ w_mask,
    const float* __restrict__ b_mask,
    float* __restrict__ out)
{
    const int g  = blockIdx.x;
    const int b  = g & 7;          // image per XCD (round-robin dispatch)
    const int h0 = (g >> 3) * RPB; // strip start row
    const int t  = threadIdx.x;

    __shared__ uint4 st[3 * 256 * 8];   // 96 KB ring: [slot][px][chunk]
    __shared__ uint4 stt[256 * 8];      // 32 KB: part/pw/pi early, S^T late

    float4* part = (float4*)stt;           // [4][256] 16 KB
    float4* pw_s = (float4*)(stt + 1024);  // [256]     4 KB
    int4*   pi_s = (int4*)(stt + 1280);    // [256]     4 KB

    const float* __restrict__ xb = x + (size_t)b * C_ * HW_;

    // staging decomposition (fixed per thread): chunk sj, pixel pair px0
    const int sj  = t >> 7;        // chunk 0..7 (8 ch)
    const int px0 = (t & 127) * 2;

    // ---- stage helpers: issue (global->reg) and write (reg->LDS ring) ----
    auto stage_issue = [&](int y, float2* v) {
        const int yc = min(max(y, 0), H_ - 1);
        const float* __restrict__ s0 = xb + (size_t)(sj * 8) * HW_ + yc * W_ + px0;
#pragma unroll
        for (int e = 0; e < 8; ++e)
            v[e] = *(const float2*)(s0 + (size_t)e * HW_);
    };
    auto stage_write = [&](int y, const float2* v) {
        const int slot = (y + 3) % 3;        // y >= -1
        union { uint4 u; _Float16 hh[8]; } e0, e1;
#pragma unroll
        for (int e = 0; e < 8; ++e) {
            e0.hh[e] = (_Float16)v[e].x;
            e1.hh[e] = (_Float16)v[e].y;
        }
        st[(slot * 256 + px0)     * 8 + (sj ^ swz(px0)    )] = e0.u;
        st[(slot * 256 + px0 + 1) * 8 + (sj ^ swz(px0 + 1))] = e1.u;
    };

    // ---- hoisted GEMM A-fragments (row-invariant): 16 oc per wave ----
    const int lane = t & 63;
    const int wv_  = t >> 6;                 // 0..15
    const int ocq  = wv_ >> 2;               // 16-oc block owned by this wave
    const int wq   = wv_ & 3;                // 64-px quarter
    const int lrow = lane >> 4;
    const int lcol = lane & 15;

    h8v afrag[2];
#pragma unroll
    for (int kk = 0; kk < 2; ++kk) {
        const int oc = ocq * 16 + lcol;
        const int c0 = kk * 32 + lrow * 8;
        const float4* wp = (const float4*)(w_conv + oc * C_ + c0);
        const float4 lo = wp[0];
        const float4 hi = wp[1];
        h8v a;
        a[0] = (_Float16)lo.x; a[1] = (_Float16)lo.y;
        a[2] = (_Float16)lo.z; a[3] = (_Float16)lo.w;
        a[4] = (_Float16)hi.x; a[5] = (_Float16)hi.y;
        a[6] = (_Float16)hi.z; a[7] = (_Float16)hi.w;
        afrag[kk] = a;
    }

    // ---- prologue: stage logical rows h0-1, h0, h0+1 ----
    {
        float2 v0[8], v1[8], v2[8];
        stage_issue(h0 - 1, v0);
        stage_issue(h0,     v1);
        stage_issue(h0 + 1, v2);
        stage_write(h0 - 1, v0);
        stage_write(h0,     v1);
        stage_write(h0 + 1, v2);
    }
    __syncthreads();

    const int px = t & 255;
    const int cq = t >> 8;                   // 0..3: 16-ch quarter

    for (int h = h0; h < h0 + RPB; ++h) {
        // ---- issue next-row stage loads early (hide under B+C) ----
        float2 sv[8];
        const bool do_stage = (h < h0 + RPB - 1);   // last needed row = h0+8
        if (do_stage) stage_issue(h + 2, sv);

        // ---- Phase B: offset/mask logits from ring slot of row h ----
        const int slot_h = h % 3;
        {
            float oy = 0.f, ox = 0.f, ml = 0.f;
#pragma unroll
            for (int k = 0; k < 2; ++k) {
                const int j = cq * 2 + k;
                union { uint4 u; _Float16 hh[8]; } blk;
                blk.u = st[(slot_h * 256 + px) * 8 + (j ^ swz(px))];
#pragma unroll
                for (int e = 0; e < 8; ++e) {
                    const float v = (float)blk.hh[e];
                    const int c = j * 8 + e;   // wave-uniform -> s_load weights
                    oy = fmaf(w_off[c],      v, oy);
                    ox = fmaf(w_off[C_ + c], v, ox);
                    ml = fmaf(w_mask[c],     v, ml);
                }
            }
            part[cq * 256 + px] = (float4){oy, ox, ml, 0.f};
        }
        __syncthreads();                               // bar1

        if (t < 256) {
            const float4 p0 = part[t];
            const float4 p1 = part[256 + t];
            const float4 p2 = part[512 + t];
            const float4 p3 = part[768 + t];
            const float oyf = p0.x + p1.x + p2.x + p3.x + b_off[0];
            const float oxf = p0.y + p1.y + p2.y + p3.y + b_off[1];
            const float mlf = p0.z + p1.z + p2.z + p3.z + b_mask[0];
            const float m = 1.0f / (1.0f + __expf(-mlf));

            const float py  = (float)h + oyf;
            const float pxf = (float)t + oxf;
            const float y0f = floorf(py), x0f = floorf(pxf);
            const float wy1 = py - y0f, wx1 = pxf - x0f;
            const float wy0 = 1.0f - wy1, wx0 = 1.0f - wx1;
            const int y0 = (int)y0f, x0 = (int)x0f;
            const int y1 = y0 + 1,   x1 = x0 + 1;
            const float vy0 = (y0 >= 0 && y0 < H_) ? 1.0f : 0.0f;
            const float vy1 = (y1 >= 0 && y1 < H_) ? 1.0f : 0.0f;
            const float vx0 = (x0 >= 0 && x0 < W_) ? 1.0f : 0.0f;
            const float vx1 = (x1 >= 0 && x1 < W_) ? 1.0f : 0.0f;
            const int x0c = min(max(x0, 0), W_ - 1);
            const int x1c = min(max(x1, 0), W_ - 1);
            pw_s[t] = (float4){wy0 * wx0 * vy0 * vx0 * m,
                               wy0 * wx1 * vy0 * vx1 * m,
                               wy1 * wx0 * vy1 * vx0 * m,
                               wy1 * wx1 * vy1 * vx1 * m};
            pi_s[t] = (int4){y0, x0c, x1c, 0};
        }
        __syncthreads();                               // bar2

        const float4 wv4 = pw_s[px];
        const int4   iv  = pi_s[px];
        __syncthreads();                               // bar2b: stt now free

        // ---- Phase C: bilinear gather from ring (+ rare global fallback) ----
        {
            const int y0  = iv.x, x0c = iv.y, x1c = iv.z;
            const int sA  = y0 - (h - 1);              // 0..2 if in window
            const int sB  = sA + 1;
            const bool inA = (unsigned)sA <= 2u;
            const bool inB = (unsigned)sB <= 2u;
            const int slotA = (y0 + 3) % 3;            // valid when inA
            const int slotB = (y0 + 4) % 3;            // valid when inB
            const int y0c = min(max(y0, 0), H_ - 1);
            const int y1c = min(max(y0 + 1, 0), H_ - 1);

            h2v W00, W01, W10, W11;
            W00[0] = W00[1] = (_Float16)wv4.x;
            W01[0] = W01[1] = (_Float16)wv4.y;
            W10[0] = W10[1] = (_Float16)wv4.z;
            W11[0] = W11[1] = (_Float16)wv4.w;

#pragma unroll
            for (int k = 0; k < 2; ++k) {
                const int j = cq * 2 + k;              // chunk 0..7
                uint4 uA0, uA1, uB0, uB1;
                if (inA) {
                    uA0 = st[(slotA * 256 + x0c) * 8 + (j ^ swz(x0c))];
                    uA1 = st[(slotA * 256 + x1c) * 8 + (j ^ swz(x1c))];
                } else {
                    const float* p0 = xb + (size_t)(j * 8) * HW_ + y0c * W_;
                    union { h2v hp[4]; uint4 u; } t0, t1;
#pragma unroll
                    for (int e = 0; e < 4; ++e) {
                        t0.hp[e][0] = (_Float16)p0[(size_t)(2 * e)     * HW_ + x0c];
                        t0.hp[e][1] = (_Float16)p0[(size_t)(2 * e + 1) * HW_ + x0c];
                        t1.hp[e][0] = (_Float16)p0[(size_t)(2 * e)     * HW_ + x1c];
                        t1.hp[e][1] = (_Float16)p0[(size_t)(2 * e + 1) * HW_ + x1c];
                    }
                    uA0 = t0.u; uA1 = t1.u;
                }
                if (inB) {
                    uB0 = st[(slotB * 256 + x0c) * 8 + (j ^ swz(x0c))];
                    uB1 = st[(slotB * 256 + x1c) * 8 + (j ^ swz(x1c))];
                } else {
                    const float* p1 = xb + (size_t)(j * 8) * HW_ + y1c * W_;
                    union { h2v hp[4]; uint4 u; } t0, t1;
#pragma unroll
                    for (int e = 0; e < 4; ++e) {
                        t0.hp[e][0] = (_Float16)p1[(size_t)(2 * e)     * HW_ + x0c];
                        t0.hp[e][1] = (_Float16)p1[(size_t)(2 * e + 1) * HW_ + x0c];
                        t1.hp[e][0] = (_Float16)p1[(size_t)(2 * e)     * HW_ + x1c];
                        t1.hp[e][1] = (_Float16)p1[(size_t)(2 * e + 1) * HW_ + x1c];
                    }
                    uB0 = t0.u; uB1 = t1.u;
                }
                union { uint4 u; h2v p[4]; } a0, a1, a2, a3, s;
                a0.u = uA0; a1.u = uA1; a2.u = uB0; a3.u = uB1;
#pragma unroll
                for (int w2 = 0; w2 < 4; ++w2)
                    s.p[w2] = W00 * a0.p[w2] + W01 * a1.p[w2]
                            + W10 * a2.p[w2] + W11 * a3.p[w2];
                stt[px * 8 + (j ^ swz(px))] = s.u;
            }
        }
        __syncthreads();                               // bar3

        // ---- write-late: stage row h+2 into the slot freed at bar3 ----
        if (do_stage) stage_write(h + 2, sv);

        // ---- Phase D: GEMM via mfma_f32_16x16x32_f16, 8 MFMA/wave ----
        f32x4 acc[4];
#pragma unroll
        for (int nt = 0; nt < 4; ++nt)
            acc[nt] = (f32x4){0.f, 0.f, 0.f, 0.f};

#pragma unroll
        for (int nt = 0; nt < 4; ++nt) {
            const int p2g = wq * 64 + nt * 16 + lcol;  // B: n = lcol
#pragma unroll
            for (int kk = 0; kk < 2; ++kk) {
                const int cblk = kk * 4 + lrow;        // B: k = lrow*8+j
                union { uint4 u; h8v v; } bb;
                bb.u = stt[p2g * 8 + (cblk ^ swz(p2g))];
                acc[nt] = __builtin_amdgcn_mfma_f32_16x16x32_f16(
                    afrag[kk], bb.v, acc[nt], 0, 0, 0);
            }
        }

        // ---- epilogue: C/D layout col=lane&15, row=(lane>>4)*4+r ----
        float* __restrict__ ob = out + (size_t)b * OC_ * HW_ + h * W_;
        const int ocb = ocq * 16 + lrow * 4;
#pragma unroll
        for (int nt = 0; nt < 4; ++nt) {
            const int p2g = wq * 64 + nt * 16 + lcol;
            const f32x4 a = acc[nt];
#pragma unroll
            for (int r = 0; r < 4; ++r)
                ob[(size_t)(ocb + r) * HW_ + p2g] = a[r];
        }
        __syncthreads();                               // bar_end
    }
}

extern "C" void kernel_launch(void* const* d_in, const int* in_sizes, int n_in,
                              void* d_out, int out_size, void* d_ws, size_t ws_size,
                              hipStream_t stream) {
    const float* x      = (const float*)d_in[0];
    const float* w_conv = (const float*)d_in[1];
    const float* w_off  = (const float*)d_in[2];
    const float* b_off  = (const float*)d_in[3];
    const float* w_mask = (const float*)d_in[4];
    const float* b_mask = (const float*)d_in[5];
    float* out = (float*)d_out;

    // 256 persistent blocks: 8 images x 32 strips, image = blockIdx & 7 (XCD).
    // No d_ws use: avoids the harness's 512 MiB per-iteration poison fill.
    dcn_fused<<<dim3(B_ * H_ / RPB), dim3(1024), 0, stream>>>(
        x, w_conv, w_off, b_off, w_mask, b_mask, out);
}

// Round 9
// 285.450 us; speedup vs baseline: 1.3156x; 1.3156x over previous
//
#include <hip/hip_runtime.h>

#define B_  8
#define C_  64
#define OC_ 64
#define H_  256
#define W_  256
#define HW_ (H_ * W_)
#define TPX 128          // output px per block (half row)
#define SPX 160          // staged px per row (16-px halo each side)

typedef __attribute__((ext_vector_type(4))) float f32x4;
typedef _Float16 h2v __attribute__((ext_vector_type(2)));  // packed fp16 pair
typedef _Float16 h8v __attribute__((ext_vector_type(8)));  // MFMA f16 A/B frag

// chunk-slot swizzle: spreads the 8 16B channel-chunks of a pixel across
// banks keyed by pixel (XOR involution within the 8-slot group).
__device__ __forceinline__ int swz(int p) { return (p ^ (p >> 3)) & 7; }

// ============================================================================
// Round-11. Ring post-mortem: persistent strips destroyed cross-block L2/L3
// temporal reuse (FETCH 66->253 MB) and amplified writes 2.09x; VALUBusy
// collapsed to 6.5%. Lesson: keep SHORT-LIVED blocks (round-5 shape), attack
// the barrier-serialized latency instead:
//   - half-row tiles: 4096 blocks x 512 thr; stage 3 rows x 160 px x 64 ch
//     fp16 (60 KB) + S^T 16 KB = 76 KB LDS -> 2 blocks/CU co-resident, so
//     one block's stalls hide under the other (the overlap round-5 lacked).
//   - barriers 5 -> 2: offset-dot reduced by 4-lane __shfl_xor butterfly
//     (thread = px x ch-quarter); pw/pi stay in registers (bit-identical
//     across the 4 lanes: butterfly order is commutative-safe).
//   - phases: A stage | bar1 | B dot+setup (regs) | C gather->S^T | bar2 |
//     D MFMA GEMM + store. Gather outside the 3-row x 160-px window falls
//     back to exact global loads (correct for arbitrary offsets).
// ============================================================================
__global__ __launch_bounds__(512, 4) void dcn_fused(
    const float* __restrict__ x,
    const float* __restrict__ w_conv,
    const float* __restrict__ w_off,
    const float* __restrict__ b_off,
    const float* __restrict__ w_mask,
    const float* __restrict__ b_mask,
    float* __restrict__ out)
{
    const int g    = blockIdx.x;
    const int b    = g & 7;              // image per XCD (round-robin)
    const int rest = g >> 3;             // 0..511
    const int h    = rest >> 1;
    const int W0   = (rest & 1) * TPX;   // half-row base
    const int t    = threadIdx.x;

    __shared__ uint4 st[3 * SPX * 8];    // 60 KB: [r][lpx][chunk] 8ch fp16
    __shared__ uint4 stt[TPX * 8];       // 16 KB: S^T[opx][chunk]

    const float* __restrict__ xb = x + (size_t)b * C_ * HW_;

    // ---- Phase A: stage rows h-1..h+1, px window [W0-16, W0+144) ----
    // unit = (r, chunk sj, px-pair p): 3*8*80 = 1920 units, 4 rounds.
#pragma unroll
    for (int i = 0; i < 4; ++i) {
        const int u = t + i * 512;
        if (u < 1920) {
            const int r  = u / 640;
            const int q  = u - r * 640;
            const int sj = q / 80;           // chunk 0..7
            const int p  = q - sj * 80;      // px-pair 0..79
            const int yc = min(max(h - 1 + r, 0), H_ - 1);
            const int gx = W0 - 16 + p * 2;
            const int gxc = min(max(gx, 0), W_ - 2);   // pair-start clamp
            const float* __restrict__ s0 =
                xb + (size_t)(sj * 8) * HW_ + yc * W_ + gxc;
            float2 v[8];
#pragma unroll
            for (int e = 0; e < 8; ++e)
                v[e] = *(const float2*)(s0 + (size_t)e * HW_);
            union { uint4 u4; _Float16 hh[8]; } e0, e1;
#pragma unroll
            for (int e = 0; e < 8; ++e) {
                e0.hh[e] = (_Float16)v[e].x;
                e1.hh[e] = (_Float16)v[e].y;
            }
            const int lpx = p * 2;
            st[(r * SPX + lpx)     * 8 + (sj ^ swz(lpx))]     = e0.u4;
            st[(r * SPX + lpx + 1) * 8 + (sj ^ swz(lpx + 1))] = e1.u4;
        }
    }
    __syncthreads();                                   // bar1: stage ready

    // ---- Phase B: offset/mask dot (thread = px x ch-quarter) ----
    const int opx  = t >> 2;             // 0..127 output-local px
    const int qc   = t & 3;              // ch-quarter (16 ch)
    const int lpxh = opx + 16;           // local px of row h in stage window
    float oy = 0.f, ox = 0.f, ml = 0.f;
#pragma unroll
    for (int k = 0; k < 2; ++k) {
        const int j = qc * 2 + k;
        union { uint4 u4; _Float16 hh[8]; } blk;
        blk.u4 = st[(SPX + lpxh) * 8 + (j ^ swz(lpxh))];   // row h = slot 1
#pragma unroll
        for (int e = 0; e < 8; ++e) {
            const float v = (float)blk.hh[e];
            const int c = j * 8 + e;
            oy = fmaf(w_off[c],      v, oy);
            ox = fmaf(w_off[C_ + c], v, ox);
            ml = fmaf(w_mask[c],     v, ml);
        }
    }
    // 4-lane butterfly: all 4 lanes end with bit-identical sums.
    oy += __shfl_xor(oy, 1); oy += __shfl_xor(oy, 2);
    ox += __shfl_xor(ox, 1); ox += __shfl_xor(ox, 2);
    ml += __shfl_xor(ml, 1); ml += __shfl_xor(ml, 2);
    oy += b_off[0]; ox += b_off[1]; ml += b_mask[0];
    const float m = 1.0f / (1.0f + __expf(-ml));

    const float py  = (float)h + oy;
    const float pxf = (float)(W0 + opx) + ox;
    const float y0f = floorf(py), x0f = floorf(pxf);
    const float wy1 = py - y0f, wx1 = pxf - x0f;
    const float wy0 = 1.0f - wy1, wx0 = 1.0f - wx1;
    const int y0 = (int)y0f, x0 = (int)x0f;
    const int y1 = y0 + 1,   x1 = x0 + 1;
    const float vy0 = (y0 >= 0 && y0 < H_) ? 1.0f : 0.0f;
    const float vy1 = (y1 >= 0 && y1 < H_) ? 1.0f : 0.0f;
    const float vx0 = (x0 >= 0 && x0 < W_) ? 1.0f : 0.0f;
    const float vx1 = (x1 >= 0 && x1 < W_) ? 1.0f : 0.0f;
    const int x0c = min(max(x0, 0), W_ - 1);
    const int x1c = min(max(x1, 0), W_ - 1);
    const float w00 = wy0 * wx0 * vy0 * vx0 * m;
    const float w01 = wy0 * wx1 * vy0 * vx1 * m;
    const float w10 = wy1 * wx0 * vy1 * vx0 * m;
    const float w11 = wy1 * wx1 * vy1 * vx1 * m;

    // ---- Phase C: gather from staged window (+ exact global fallback) ----
    {
        const int sA = y0 - (h - 1), sB = sA + 1;      // staged slots
        const int lA = x0c - W0 + 16, lB = x1c - W0 + 16;
        const bool inA = (unsigned)sA <= 2u;
        const bool inB = (unsigned)sB <= 2u;
        const bool inXA = (unsigned)lA < SPX;
        const bool inXB = (unsigned)lB < SPX;
        const int y0c = min(max(y0, 0), H_ - 1);
        const int y1c = min(max(y1, 0), H_ - 1);

        auto gfall = [&](int yc, int xc, int j) -> uint4 {
            const float* __restrict__ p = xb + (size_t)(j * 8) * HW_ + yc * W_ + xc;
            union { uint4 u4; _Float16 hh[8]; } r;
#pragma unroll
            for (int e = 0; e < 8; ++e)
                r.hh[e] = (_Float16)p[(size_t)e * HW_];
            return r.u4;
        };

        h2v W00, W01, W10, W11;
        W00[0] = W00[1] = (_Float16)w00;
        W01[0] = W01[1] = (_Float16)w01;
        W10[0] = W10[1] = (_Float16)w10;
        W11[0] = W11[1] = (_Float16)w11;

#pragma unroll
        for (int k = 0; k < 2; ++k) {
            const int j = qc * 2 + k;
            const uint4 c00 = (inA && inXA) ? st[(sA * SPX + lA) * 8 + (j ^ swz(lA))]
                                            : gfall(y0c, x0c, j);
            const uint4 c01 = (inA && inXB) ? st[(sA * SPX + lB) * 8 + (j ^ swz(lB))]
                                            : gfall(y0c, x1c, j);
            const uint4 c10 = (inB && inXA) ? st[(sB * SPX + lA) * 8 + (j ^ swz(lA))]
                                            : gfall(y1c, x0c, j);
            const uint4 c11 = (inB && inXB) ? st[(sB * SPX + lB) * 8 + (j ^ swz(lB))]
                                            : gfall(y1c, x1c, j);
            union { uint4 u4; h2v p[4]; } a0, a1, a2, a3, s;
            a0.u4 = c00; a1.u4 = c01; a2.u4 = c10; a3.u4 = c11;
#pragma unroll
            for (int w2 = 0; w2 < 4; ++w2)
                s.p[w2] = W00 * a0.p[w2] + W01 * a1.p[w2]
                        + W10 * a2.p[w2] + W11 * a3.p[w2];
            stt[opx * 8 + (j ^ swz(opx))] = s.u4;
        }
    }

    // ---- Phase D setup: A fragments (w_conv f32->f16, L2-hot) ----
    const int lane = t & 63;
    const int wv_  = t >> 6;             // 0..7
    const int ocq  = wv_ >> 1;           // 16-oc block
    const int wh   = wv_ & 1;            // 64-px half of the tile
    const int lrow = lane >> 4;
    const int lcol = lane & 15;

    h8v afrag[2];
#pragma unroll
    for (int kk = 0; kk < 2; ++kk) {
        const int oc = ocq * 16 + lcol;
        const int c0 = kk * 32 + lrow * 8;
        const float4* wp = (const float4*)(w_conv + oc * C_ + c0);
        const float4 lo = wp[0];
        const float4 hi = wp[1];
        h8v a;
        a[0] = (_Float16)lo.x; a[1] = (_Float16)lo.y;
        a[2] = (_Float16)lo.z; a[3] = (_Float16)lo.w;
        a[4] = (_Float16)hi.x; a[5] = (_Float16)hi.y;
        a[6] = (_Float16)hi.z; a[7] = (_Float16)hi.w;
        afrag[kk] = a;
    }

    __syncthreads();                                   // bar2: S^T ready

    // ---- Phase D: GEMM via mfma_f32_16x16x32_f16, 8 MFMA/wave ----
    f32x4 acc[4];
#pragma unroll
    for (int nt = 0; nt < 4; ++nt)
        acc[nt] = (f32x4){0.f, 0.f, 0.f, 0.f};

#pragma unroll
    for (int nt = 0; nt < 4; ++nt) {
        const int p2 = wh * 64 + nt * 16 + lcol;       // B: n = lcol
#pragma unroll
        for (int kk = 0; kk < 2; ++kk) {
            const int cblk = kk * 4 + lrow;            // B: k = lrow*8+j
            union { uint4 u4; h8v v; } bb;
            bb.u4 = stt[p2 * 8 + (cblk ^ swz(p2))];
            acc[nt] = __builtin_amdgcn_mfma_f32_16x16x32_f16(
                afrag[kk], bb.v, acc[nt], 0, 0, 0);
        }
    }

    // ---- Epilogue: C/D layout col=lane&15, row=(lane>>4)*4+r ----
    float* __restrict__ ob = out + (size_t)b * OC_ * HW_ + h * W_ + W0;
    const int ocb = ocq * 16 + lrow * 4;
#pragma unroll
    for (int nt = 0; nt < 4; ++nt) {
        const int p2 = wh * 64 + nt * 16 + lcol;
        const f32x4 a = acc[nt];
#pragma unroll
        for (int r = 0; r < 4; ++r)
            ob[(size_t)(ocb + r) * HW_ + p2] = a[r];
    }
}

extern "C" void kernel_launch(void* const* d_in, const int* in_sizes, int n_in,
                              void* d_out, int out_size, void* d_ws, size_t ws_size,
                              hipStream_t stream) {
    const float* x      = (const float*)d_in[0];
    const float* w_conv = (const float*)d_in[1];
    const float* w_off  = (const float*)d_in[2];
    const float* b_off  = (const float*)d_in[3];
    const float* w_mask = (const float*)d_in[4];
    const float* b_mask = (const float*)d_in[5];
    float* out = (float*)d_out;

    // 4096 short-lived blocks: 8 img x 256 rows x 2 half-rows; img = bid&7.
    // No d_ws use: avoids the harness's 512 MiB per-iteration poison fill.
    dcn_fused<<<dim3(B_ * H_ * 2), dim3(512), 0, stream>>>(
        x, w_conv, w_off, b_off, w_mask, b_mask, out);
}